// Round 4
// baseline (72.860 us; speedup 1.0000x reference)
//
#include <hip/hip_runtime.h>
#include <stdint.h>

typedef unsigned int uint;
typedef unsigned short ushort;

#define NPTS  262144
#define PLANE_T_ELEMS (65536 * 32)
#define WS_PLANES_BYTES ((size_t)3 * PLANE_T_ELEMS * 2)   // 12582912
#define WS_GRB_OFF  WS_PLANES_BYTES
#define WS_NEEDED   (WS_PLANES_BYTES + (size_t)32768 * 2)

typedef __attribute__((ext_vector_type(8))) short bf16x8;   // 8 bf16 = 4 VGPR
typedef __attribute__((ext_vector_type(4))) float f32x4;
typedef __attribute__((ext_vector_type(2))) float f32x2;

__device__ __forceinline__ ushort f2bf(float f) {
  union { float f; uint u; } v; v.f = f;
  uint r = v.u + 0x7fffu + ((v.u >> 16) & 1u);   // RNE
  return (ushort)(r >> 16);
}
__device__ __forceinline__ float bf_lo(uint u) {
  union { uint u; float f; } v; v.u = u << 16; return v.f;
}
__device__ __forceinline__ float bf_hi(uint u) {
  union { uint u; float f; } v; v.u = u & 0xffff0000u; return v.f;
}
__device__ __forceinline__ void pkfma(f32x2& a, f32x2 d, f32x2 y) {
  asm("v_pk_fma_f32 %0, %1, %2, %0" : "+v"(a) : "v"(d), "v"(y));
}

// ---------- prep kernels (unchanged, verified) ----------

// (C,H,W) fp32 -> (H,W,C) bf16, C=32 contiguous per texel (64B)
__global__ __launch_bounds__(256) void transpose_planes_k(
    const float* __restrict__ pxy, const float* __restrict__ pyz,
    const float* __restrict__ pxz, ushort* __restrict__ out) {
  int plane = blockIdx.x >> 8;
  int h = blockIdx.x & 255;
  const float* src = (plane == 0) ? pxy : (plane == 1) ? pyz : pxz;
  int w = threadIdx.x;
  int p = (h << 8) + w;
  uint vals[16];
#pragma unroll
  for (int c = 0; c < 32; c += 2) {
    float f0 = src[(size_t)c * 65536 + p];
    float f1 = src[(size_t)(c + 1) * 65536 + p];
    vals[c >> 1] = (uint)f2bf(f0) | ((uint)f2bf(f1) << 16);
  }
  uint4* d4 = (uint4*)(out + (size_t)plane * PLANE_T_ELEMS + (size_t)p * 32);
#pragma unroll
  for (int i = 0; i < 4; ++i)
    d4[i] = make_uint4(vals[4 * i], vals[4 * i + 1], vals[4 * i + 2], vals[4 * i + 3]);
}

// G[x][y][z] -> fragment-ordered bf16 table (A operand: row=x, k=z):
// e = ((y*2+xh)*64 + l)*8 + j  ->  G[x= xh*16+(l&15)][y][z= (l>>4)*8+j]
__global__ __launch_bounds__(256) void prep_grb_k(const float* __restrict__ g,
                                                  ushort* __restrict__ grb) {
  int e = blockIdx.x * 256 + threadIdx.x;   // 0..32767
  int j = e & 7;
  int l = (e >> 3) & 63;
  int xh = (e >> 9) & 1;
  int y = e >> 10;
  int x = xh * 16 + (l & 15);
  int z = ((l >> 4) << 3) + j;
  grb[e] = f2bf(g[x * 1024 + y * 32 + z]);
}

// ---------- bilinear sampler (verified) ----------
template <bool BIG, class F>
__device__ __forceinline__ void sample_plane(const ushort* __restrict__ bt,
                                             const float* __restrict__ bf,
                                             float gw, float gh, F store) {
  float fx = (gw + 1.0f) * 0.5f * 255.0f;
  float fy = (gh + 1.0f) * 0.5f * 255.0f;
  float fx0 = floorf(fx), fy0 = floorf(fy);
  float wx1 = fx - fx0, wy1 = fy - fy0;
  float wx0 = 1.0f - wx1, wy0 = 1.0f - wy1;
  int ix0 = (int)fx0, iy0 = (int)fy0;
  int ix1 = ix0 + 1, iy1 = iy0 + 1;
  bool vx0 = (ix0 >= 0) & (ix0 < 256);
  bool vx1 = (ix1 >= 0) & (ix1 < 256);
  bool vy0 = (iy0 >= 0) & (iy0 < 256);
  bool vy1 = (iy1 >= 0) & (iy1 < 256);
  float w00 = (vx0 & vy0) ? wx0 * wy0 : 0.0f;
  float w10 = (vx1 & vy0) ? wx1 * wy0 : 0.0f;
  float w01 = (vx0 & vy1) ? wx0 * wy1 : 0.0f;
  float w11 = (vx1 & vy1) ? wx1 * wy1 : 0.0f;
  int cx0 = min(max(ix0, 0), 255), cx1 = min(max(ix1, 0), 255);
  int cy0 = min(max(iy0, 0), 255), cy1 = min(max(iy1, 0), 255);
  if (BIG) {
    // 32-bit byte offsets + uniform base -> saddr-form loads
    uint o00 = (uint)(((cy0 << 8) + cx0) * 64);
    uint o10 = (uint)(((cy0 << 8) + cx1) * 64);
    uint o01 = (uint)(((cy1 << 8) + cx0) * 64);
    uint o11 = (uint)(((cy1 << 8) + cx1) * 64);
    const char* base = (const char*)bt;
#pragma unroll
    for (int cc = 0; cc < 2; ++cc) {
      uint4 a = *(const uint4*)(base + o00 + cc * 16 + 0);
      uint4 a2 = *(const uint4*)(base + o00 + cc * 32 + 16);
      (void)a2;
      break;
    }
#pragma unroll
    for (int cc = 0; cc < 32; cc += 8) {
      uint4 a = *(const uint4*)(base + o00 + cc * 2);
      uint4 b = *(const uint4*)(base + o10 + cc * 2);
      uint4 c = *(const uint4*)(base + o01 + cc * 2);
      uint4 d = *(const uint4*)(base + o11 + cc * 2);
      const uint* pa = (const uint*)&a; const uint* pb = (const uint*)&b;
      const uint* pc = (const uint*)&c; const uint* pd = (const uint*)&d;
#pragma unroll
      for (int j = 0; j < 4; ++j) {
        float v0 = w00 * bf_lo(pa[j]) + w10 * bf_lo(pb[j]) +
                   w01 * bf_lo(pc[j]) + w11 * bf_lo(pd[j]);
        float v1 = w00 * bf_hi(pa[j]) + w10 * bf_hi(pb[j]) +
                   w01 * bf_hi(pc[j]) + w11 * bf_hi(pd[j]);
        store(cc + 2 * j, v0);
        store(cc + 2 * j + 1, v1);
      }
    }
  } else {
    int o00 = (cy0 << 8) + cx0, o10 = (cy0 << 8) + cx1;
    int o01 = (cy1 << 8) + cx0, o11 = (cy1 << 8) + cx1;
#pragma unroll
    for (int c = 0; c < 32; ++c) {
      const float* base = bf + (size_t)c * 65536;
      float v = w00 * base[o00] + w10 * base[o10] + w01 * base[o01] + w11 * base[o11];
      store(c, v);
    }
  }
}

// ---------- MFMA main kernel: A=G (no build), B=xz from LDS, y-scale on pk_fma ----------
__global__ __launch_bounds__(128) void tucker_mfma_k(
    const float* __restrict__ coords,
    const ushort* __restrict__ planes_t,
    const ushort* __restrict__ grb,
    float* __restrict__ out) {
  __shared__ ushort xy_s[128][36];   // 72B rows: 18-bank stride, conflict-free dwords
  __shared__ ushort xz_s[128][32];   // 64B rows: b128-aligned (B fragments)
  __shared__ ushort yz_s[128][36];

  int tid = threadIdx.x;
  int p = blockIdx.x * 128 + tid;
  float c0c = coords[3 * p + 0] * (1.0f / 1.3f);
  float c1c = coords[3 * p + 1] * (1.0f / 1.3f);
  float c2c = coords[3 * p + 2] * (1.0f / 1.3f);

  {
    uint buf[16];
    auto pack = [&](int c, float v) {
      ushort h = f2bf(v);
      if (c & 1) buf[c >> 1] |= ((uint)h << 16);
      else buf[c >> 1] = (uint)h;
    };
    // xy: W<-x(c0), H<-y(c1)
    sample_plane<true>(planes_t, nullptr, c0c, c1c, pack);
    uint2* r2 = (uint2*)xy_s[tid];
#pragma unroll
    for (int i = 0; i < 8; ++i) r2[i] = make_uint2(buf[2 * i], buf[2 * i + 1]);
    // yz: W<-y(c1), H<-z(c2)
    sample_plane<true>(planes_t + (size_t)PLANE_T_ELEMS, nullptr, c1c, c2c, pack);
    r2 = (uint2*)yz_s[tid];
#pragma unroll
    for (int i = 0; i < 8; ++i) r2[i] = make_uint2(buf[2 * i], buf[2 * i + 1]);
    // xz: W<-x(c0), H<-z(c2)
    sample_plane<true>(planes_t + (size_t)2 * PLANE_T_ELEMS, nullptr, c0c, c2c, pack);
    uint4* r4 = (uint4*)xz_s[tid];
#pragma unroll
    for (int i = 0; i < 4; ++i)
      r4[i] = make_uint4(buf[4 * i], buf[4 * i + 1], buf[4 * i + 2], buf[4 * i + 3]);
  }
  __syncthreads();

  int l = tid & 63;
  int wb = tid & 64;       // wave's row base in block LDS
  int s = l & 15;          // point-in-tile (B col / D col)
  int kb = l >> 4;         // k/row block

  // B fragments: lane's xz bf16x8 per tile (direct from LDS, zero VALU build)
  union BF { uint4 u; bf16x8 v; } bfrag[4];
#pragma unroll
  for (int t = 0; t < 4; ++t)
    bfrag[t].u = ((const uint4*)xz_s[wb + t * 16 + s])[kb];

  const ushort* yzr[4];
#pragma unroll
  for (int t = 0; t < 4; ++t) yzr[t] = yz_s[wb + t * 16 + s];

  // acc[t][pair]: pairs 0,1 -> x = kb*4+{0,1},{2,3}; pairs 2,3 -> x = 16+kb*4+...
  f32x2 acc[4][4];
#pragma unroll
  for (int t = 0; t < 4; ++t)
#pragma unroll
    for (int j = 0; j < 4; ++j) acc[t][j] = (f32x2){0.f, 0.f};

  const char* gb = (const char*)grb;
  uint lo16 = (uint)l * 16;
  f32x4 zero = {0.f, 0.f, 0.f, 0.f};

#pragma unroll
  for (int yy = 0; yy < 16; ++yy) {          // y = 2*yy, 2*yy+1
    bf16x8 a0 = *(const bf16x8*)(gb + (uint)(yy * 4096 + 0)    + lo16);  // y0, x00-15
    bf16x8 a1 = *(const bf16x8*)(gb + (uint)(yy * 4096 + 1024) + lo16);  // y0, x16-31
    bf16x8 a2 = *(const bf16x8*)(gb + (uint)(yy * 4096 + 2048) + lo16);  // y1, x00-15
    bf16x8 a3 = *(const bf16x8*)(gb + (uint)(yy * 4096 + 3072) + lo16);  // y1, x16-31
#pragma unroll
    for (int t = 0; t < 4; ++t) {
      uint ypair = *(const uint*)(yzr[t] + 2 * yy);   // yz[n][y0], yz[n][y1]
      float y0 = bf_lo(ypair), y1 = bf_hi(ypair);
      f32x2 yv0 = {y0, y0}, yv1 = {y1, y1};
      union { f32x4 v; f32x2 h[2]; } d;
      d.v = __builtin_amdgcn_mfma_f32_16x16x32_bf16(a0, bfrag[t].v, zero, 0, 0, 0);
      pkfma(acc[t][0], d.h[0], yv0);
      pkfma(acc[t][1], d.h[1], yv0);
      d.v = __builtin_amdgcn_mfma_f32_16x16x32_bf16(a1, bfrag[t].v, zero, 0, 0, 0);
      pkfma(acc[t][2], d.h[0], yv0);
      pkfma(acc[t][3], d.h[1], yv0);
      d.v = __builtin_amdgcn_mfma_f32_16x16x32_bf16(a2, bfrag[t].v, zero, 0, 0, 0);
      pkfma(acc[t][0], d.h[0], yv1);
      pkfma(acc[t][1], d.h[1], yv1);
      d.v = __builtin_amdgcn_mfma_f32_16x16x32_bf16(a3, bfrag[t].v, zero, 0, 0, 0);
      pkfma(acc[t][2], d.h[0], yv1);
      pkfma(acc[t][3], d.h[1], yv1);
    }
  }

  // epilogue: out[n] = sum_x xy[n][x] * W[x][n]; lane holds 8 x's for point s
  int gbase = blockIdx.x * 128 + wb;
#pragma unroll
  for (int t = 0; t < 4; ++t) {
    const uint* xyr = (const uint*)xy_s[wb + t * 16 + s];
    uint q0 = xyr[kb * 2], q1 = xyr[kb * 2 + 1];
    uint q2 = xyr[8 + kb * 2], q3 = xyr[8 + kb * 2 + 1];
    float v = acc[t][0][0] * bf_lo(q0) + acc[t][0][1] * bf_hi(q0)
            + acc[t][1][0] * bf_lo(q1) + acc[t][1][1] * bf_hi(q1)
            + acc[t][2][0] * bf_lo(q2) + acc[t][2][1] * bf_hi(q2)
            + acc[t][3][0] * bf_lo(q3) + acc[t][3][1] * bf_hi(q3);
    v += __shfl_xor(v, 16, 64);   // reduce over kb groups
    v += __shfl_xor(v, 32, 64);
    if (kb == 0) out[gbase + t * 16 + s] = v;
  }
}

// ---------- fallback (no workspace): slow-but-correct ----------
__global__ __launch_bounds__(256) void tucker_small_k(
    const float* __restrict__ coords,
    const float* __restrict__ pxy, const float* __restrict__ pyz,
    const float* __restrict__ pxz, const float* __restrict__ g,
    float* __restrict__ out) {
  __shared__ float s_yz[256 * 33];
  int tid = threadIdx.x;
  int p = blockIdx.x * 256 + tid;
  float c0 = coords[3 * p + 0] / 1.3f;
  float c1 = coords[3 * p + 1] / 1.3f;
  float c2 = coords[3 * p + 2] / 1.3f;
  float xy[32], xz[32];
  float* yzrow = &s_yz[tid * 33];
  sample_plane<false>(nullptr, pxy, c0, c1, [&](int c, float v) { xy[c] = v; });
  sample_plane<false>(nullptr, pyz, c1, c2, [&](int c, float v) { yzrow[c] = v; });
  sample_plane<false>(nullptr, pxz, c0, c2, [&](int c, float v) { xz[c] = v; });
  float acc = 0.0f;
  for (int y = 0; y < 32; ++y) {
    float yzv = yzrow[y];
    float accy = 0.0f;
#pragma unroll
    for (int z = 0; z < 32; ++z) {
      float t0 = 0.f, t1 = 0.f, t2 = 0.f, t3 = 0.f;
#pragma unroll
      for (int x = 0; x < 32; x += 4) {
        t0 = fmaf(g[(x + 0) * 1024 + y * 32 + z], xy[x + 0], t0);
        t1 = fmaf(g[(x + 1) * 1024 + y * 32 + z], xy[x + 1], t1);
        t2 = fmaf(g[(x + 2) * 1024 + y * 32 + z], xy[x + 2], t2);
        t3 = fmaf(g[(x + 3) * 1024 + y * 32 + z], xy[x + 3], t3);
      }
      accy = fmaf((t0 + t1) + (t2 + t3), xz[z], accy);
    }
    acc = fmaf(accy, yzv, acc);
  }
  out[p] = acc;
}

extern "C" void kernel_launch(void* const* d_in, const int* in_sizes, int n_in,
                              void* d_out, int out_size, void* d_ws, size_t ws_size,
                              hipStream_t stream) {
  const float* coords = (const float*)d_in[0];
  const float* pxy = (const float*)d_in[1];
  const float* pyz = (const float*)d_in[2];
  const float* pxz = (const float*)d_in[3];
  const float* g   = (const float*)d_in[4];
  float* out = (float*)d_out;

  if (ws_size >= WS_NEEDED) {
    ushort* planes_t = (ushort*)d_ws;
    ushort* grb = (ushort*)((char*)d_ws + WS_GRB_OFF);
    hipLaunchKernelGGL(transpose_planes_k, dim3(768), dim3(256), 0, stream,
                       pxy, pyz, pxz, planes_t);
    hipLaunchKernelGGL(prep_grb_k, dim3(128), dim3(256), 0, stream, g, grb);
    hipLaunchKernelGGL(tucker_mfma_k, dim3(NPTS / 128), dim3(128), 0, stream,
                       coords, planes_t, grb, out);
  } else {
    hipLaunchKernelGGL(tucker_small_k, dim3(NPTS / 256), dim3(256), 0, stream,
                       coords, pxy, pyz, pxz, g, out);
  }
}